// Round 4
// baseline (239.681 us; speedup 1.0000x reference)
//
#include <hip/hip_runtime.h>
#include <math.h>

#define BATCH 8
#define CH    256
#define H     128
#define W     128
#define HW    (H * W)          // 16384
#define OH    65
#define OW    65
#define NPIX  (OH * OW)        // 4225
#define CSPLIT 4               // channel splits per (b, oh) row
#define CPW   (CH / CSPLIT / 4) // 16 channels per wave

// Kernel 1: per-pixel channel L2 norm, float4-vectorized. HBM-bound (~21 us).
__global__ __launch_bounds__(256) void norm_kernel(const float4* __restrict__ x4,
                                                   float4* __restrict__ n4) {
    __shared__ float4 part[4][64];
    const int lane = threadIdx.x & 63;
    const int wv   = threadIdx.x >> 6;
    const int q    = blockIdx.x * 64 + lane;   // global pixel-quad index
    const int b    = (q * 4) >> 14;            // / HW
    const int qin  = q - b * (HW / 4);         // quad within image

    const float4* p = x4 + (size_t)(b * CH + wv * 64) * (HW / 4) + qin;
    float4 acc = {0.f, 0.f, 0.f, 0.f};
    #pragma unroll 8
    for (int c = 0; c < 64; ++c) {
        float4 v = p[(size_t)c * (HW / 4)];
        acc.x += v.x * v.x; acc.y += v.y * v.y;
        acc.z += v.z * v.z; acc.w += v.w * v.w;
    }
    part[wv][lane] = acc;
    __syncthreads();
    if (wv == 0) {
        float4 a0 = part[0][lane], a1 = part[1][lane];
        float4 a2 = part[2][lane], a3 = part[3][lane];
        float4 r;
        r.x = sqrtf(a0.x + a1.x + a2.x + a3.x);
        r.y = sqrtf(a0.y + a1.y + a2.y + a3.y);
        r.z = sqrtf(a0.z + a1.z + a2.z + a3.z);
        r.w = sqrtf(a0.w + a1.w + a2.w + a3.w);
        n4[q] = r;
    }
}

// Kernel 2: row-cooperative softmax-weighted 3x3 stride-2 pooling.
// Block = (oh, b, z); 4 waves x 16 channels. Lane l = output pixel l (lane 63
// also emits pixel 64). Per channel: 3 coalesced float2 row-loads; cols 2l-2,
// 2l-1 arrive via shfl_up; OOB taps have exactly-zero weights (kills lane-0
// shuffle garbage and the col-128 tap). Weights live in registers; no LDS or
// barriers inside the channel loop.
__global__ __launch_bounds__(256) void pool_kernel(const float* __restrict__ x,
                                                   const float* __restrict__ n,
                                                   float* __restrict__ out) {
    __shared__ float wts[OW][9];
    const int oh = blockIdx.x;
    const int b  = blockIdx.y;
    const int z  = blockIdx.z;
    const int t  = threadIdx.x;

    // Phase A: softmax weights for each of the 65 output pixels of this row.
    if (t < OW) {
        const float* nb = n + b * HW;
        const int iw0 = 2 * t - 2;
        float ww[9];
        bool  vl[9];
        float m = 0.f;   // OOB norms are 0 -> max starts at 0
        #pragma unroll
        for (int r = 0; r < 3; ++r) {
            int ih = 2 * oh + r - 2;
            bool vh = (unsigned)ih < (unsigned)H;
            int ihc = ih < 0 ? 0 : (ih > H - 1 ? H - 1 : ih);
            #pragma unroll
            for (int kw = 0; kw < 3; ++kw) {
                int iw = iw0 + kw;
                bool v = vh && ((unsigned)iw < (unsigned)W);
                int iwc = iw < 0 ? 0 : (iw > W - 1 ? W - 1 : iw);
                float nv = v ? nb[ihc * W + iwc] : 0.f;
                vl[r * 3 + kw] = v;
                ww[r * 3 + kw] = nv;
                m = fmaxf(m, nv);
            }
        }
        float d = 0.f;
        #pragma unroll
        for (int k = 0; k < 9; ++k) {
            float e = __expf(ww[k] - m);   // OOB contributes exp(0-m) to denom
            d += e;
            ww[k] = vl[k] ? e : 0.f;       // but zero weight in numerator
        }
        float inv = 1.f / d;
        #pragma unroll
        for (int k = 0; k < 9; ++k) wts[t][k] = ww[k] * inv;
    }
    __syncthreads();

    const int lane = t & 63;
    const int wv   = t >> 6;

    // per-lane weights for pixel `lane`, plus broadcast weights for pixel 64
    float w0[9], w64[9];
    #pragma unroll
    for (int k = 0; k < 9; ++k) { w0[k] = wts[lane][k]; w64[k] = wts[OW - 1][k]; }

    // clamped input-row byte bases (invalid rows carry zero weights)
    int rb[3];
    #pragma unroll
    for (int r = 0; r < 3; ++r) {
        int ih = 2 * oh + r - 2;
        int ihc = ih < 0 ? 0 : (ih > H - 1 ? H - 1 : ih);
        rb[r] = ihc * W;
    }

    const int cbase = z * (CH / CSPLIT) + wv * CPW;
    const float* xb = x + (size_t)(b * CH + cbase) * HW;
    float*       ob = out + (size_t)(b * CH + cbase) * NPIX + oh * OW;

    #pragma unroll 4
    for (int c = 0; c < CPW; ++c) {
        const float* xc = xb + (size_t)c * HW;
        float2 own[3], prev[3];
        #pragma unroll
        for (int r = 0; r < 3; ++r)
            own[r] = *(const float2*)(xc + rb[r] + 2 * lane);   // cols 2l, 2l+1
        #pragma unroll
        for (int r = 0; r < 3; ++r) {
            prev[r].x = __shfl_up(own[r].x, 1);                 // col 2l-2
            prev[r].y = __shfl_up(own[r].y, 1);                 // col 2l-1
        }
        float a0 = 0.f, a1 = 0.f;
        #pragma unroll
        for (int r = 0; r < 3; ++r) {
            a0 += w0[r * 3 + 0] * prev[r].x + w0[r * 3 + 1] * prev[r].y
                + w0[r * 3 + 2] * own[r].x;
            a1 += w64[r * 3 + 0] * own[r].x + w64[r * 3 + 1] * own[r].y;
            // pixel 64's third tap (col 128) is OOB -> weight 0
        }
        float* oc = ob + (size_t)c * NPIX;
        oc[lane] = a0;                       // coalesced 256 B
        if (lane == 63) oc[OW - 1] = a1;     // pixel 64 (taps = lane 63's own)
    }
}

extern "C" void kernel_launch(void* const* d_in, const int* in_sizes, int n_in,
                              void* d_out, int out_size, void* d_ws, size_t ws_size,
                              hipStream_t stream) {
    const float* x = (const float*)d_in[0];
    float* out = (float*)d_out;
    float* nbuf = (float*)d_ws;  // BATCH*H*W floats = 512 KB

    norm_kernel<<<512, 256, 0, stream>>>((const float4*)x, (float4*)nbuf);

    dim3 grid(OH, BATCH, CSPLIT);   // 65 x 8 x 4 = 2080 blocks
    pool_kernel<<<grid, 256, 0, stream>>>(x, nbuf, out);
}